// Round 1
// baseline (179.553 us; speedup 1.0000x reference)
//
#include <hip/hip_runtime.h>
#include <hip/hip_bf16.h>
#include <stdint.h>

typedef __attribute__((ext_vector_type(8))) short short8;
typedef __attribute__((ext_vector_type(4))) float floatx4;

#define FEAT_DIM 1536
#define QD 64
#define NROWS 8192
#define TT 513

__device__ __forceinline__ unsigned short f2bf(float x) {
  union { float f; unsigned u; } t; t.f = x;
  unsigned r = t.u + 0x7fffu + ((t.u >> 16) & 1u);
  return (unsigned short)(r >> 16);
}
__device__ __forceinline__ float bf2f(unsigned short u) {
  union { float f; unsigned u; } t; t.u = ((unsigned)u) << 16;
  return t.f;
}
// monotone float->uint map (order-preserving), low 4 bits freed for an index
__device__ __forceinline__ unsigned packkey(float f, int idx) {
  unsigned x = __float_as_uint(f);
  unsigned m = (unsigned)((int)x >> 31);
  unsigned u = x ^ (m | 0x80000000u);
  return (u & ~15u) | (unsigned)idx;
}
__device__ __forceinline__ float unpackkey(unsigned u) {
  u &= ~15u;
  unsigned x = (u & 0x80000000u) ? (u ^ 0x80000000u) : ~u;
  return __uint_as_float(x);
}

// K0: one-time proj -> bf16 in MFMA B-fragment order.
// prepB[((c*4+sub)*16+n)*4+q][j] = bf16(proj[(c*32+q*8+j)*64 + sub*16 + n])
// so k_sf lane (q,n) reads one contiguous short8 per (chunk, sub).
__global__ __launch_bounds__(256) void k_prep(const float* __restrict__ proj,
                                              unsigned short* __restrict__ prepB) {
  int t = blockIdx.x * 256 + threadIdx.x;   // 0..12287
  int q = t & 3, nn = (t >> 2) & 15, sub = (t >> 6) & 3, c = t >> 8;
  const float* src = proj + (size_t)(c * 32 + q * 8) * QD + sub * 16 + nn;
  union { unsigned short u[8]; short8 v; } P;
#pragma unroll
  for (int j = 0; j < 8; ++j) P.u[j] = f2bf(src[j * QD]);
  *(short8*)(prepB + (size_t)t * 8) = P.v;
}

// K1: sf = win @ proj (MFMA bf16). B fragments now pre-converted (k_prep):
// 4 coalesced 16B loads per chunk instead of 32 scalar loads + 96 f2bf.
__global__ __launch_bounds__(256, 4) void k_sf(const float* __restrict__ feat,
                                               const unsigned short* __restrict__ prepB,
                                               unsigned short* __restrict__ sfb,
                                               float* __restrict__ sq) {
  const int tid = threadIdx.x;
  const int wave = tid >> 6, lane = tid & 63;
  const int q = lane >> 4, n = lane & 15;
  const int rbase = blockIdx.x * 16;
  const int row = rbase + n;
  const int b = row >> 9, ti = row & 511;
  const float* fb = feat + (size_t)(b * TT + ti) * FEAT_DIM;
  const int kw = wave * 384;
  const short8* pb = (const short8*)prepB + (size_t)wave * 12 * 256 + n * 4 + q;

  floatx4 acc0 = {0,0,0,0}, acc1 = {0,0,0,0}, acc2 = {0,0,0,0}, acc3 = {0,0,0,0};

  int koff = kw + q * 8;
  floatx4 f0 = *(const floatx4*)(fb + koff);
  floatx4 f1 = *(const floatx4*)(fb + koff + 4);
  floatx4 g0 = *(const floatx4*)(fb + FEAT_DIM + koff);
  floatx4 g1 = *(const floatx4*)(fb + FEAT_DIM + koff + 4);
  short8 B0 = pb[0], B1 = pb[64], B2 = pb[128], B3 = pb[192];

  for (int ks = 0; ks < 12; ++ks) {
    floatx4 nf0, nf1, ng0, ng1;
    short8 nB0, nB1, nB2, nB3;
    if (ks < 11) {
      int ko = kw + (ks + 1) * 32 + q * 8;
      nf0 = *(const floatx4*)(fb + ko);
      nf1 = *(const floatx4*)(fb + ko + 4);
      ng0 = *(const floatx4*)(fb + FEAT_DIM + ko);
      ng1 = *(const floatx4*)(fb + FEAT_DIM + ko + 4);
      const short8* pn = pb + (ks + 1) * 256;
      nB0 = pn[0]; nB1 = pn[64]; nB2 = pn[128]; nB3 = pn[192];
    }
    __builtin_amdgcn_sched_barrier(0);
    union { unsigned short u[8]; short8 v; } A;
#pragma unroll
    for (int j = 0; j < 4; ++j) A.u[j] = f2bf(0.5f * (f0[j] + g0[j]));
#pragma unroll
    for (int j = 0; j < 4; ++j) A.u[4 + j] = f2bf(0.5f * (f1[j] + g1[j]));
    acc0 = __builtin_amdgcn_mfma_f32_16x16x32_bf16(A.v, B0, acc0, 0, 0, 0);
    acc1 = __builtin_amdgcn_mfma_f32_16x16x32_bf16(A.v, B1, acc1, 0, 0, 0);
    acc2 = __builtin_amdgcn_mfma_f32_16x16x32_bf16(A.v, B2, acc2, 0, 0, 0);
    acc3 = __builtin_amdgcn_mfma_f32_16x16x32_bf16(A.v, B3, acc3, 0, 0, 0);
    if (ks < 11) {
      f0 = nf0; f1 = nf1; g0 = ng0; g1 = ng1;
      B0 = nB0; B1 = nB1; B2 = nB2; B3 = nB3;
    }
  }

  __shared__ float part[4][16][64];
#pragma unroll
  for (int r = 0; r < 4; ++r) {
    part[wave][q * 4 + r][0 * 16 + n] = acc0[r];
    part[wave][q * 4 + r][1 * 16 + n] = acc1[r];
    part[wave][q * 4 + r][2 * 16 + n] = acc2[r];
    part[wave][q * 4 + r][3 * 16 + n] = acc3[r];
  }
  __syncthreads();
  {
    const int r = tid >> 4;
    const int c0 = (tid & 15) * 4;
    float sqp = 0.0f;
    union { unsigned short u[4]; uint2 d; } P;
#pragma unroll
    for (int j = 0; j < 4; ++j) {
      float v = part[0][r][c0 + j] + part[1][r][c0 + j] +
                part[2][r][c0 + j] + part[3][r][c0 + j];
      P.u[j] = f2bf(v);
      float bv = bf2f(P.u[j]);
      sqp += bv * bv;
    }
    *(uint2*)(sfb + (size_t)(rbase + r) * QD + c0) = P.d;
#pragma unroll
    for (int off = 1; off < 16; off <<= 1) sqp += __shfl_xor(sqp, off, 64);
    if ((tid & 15) == 0) sq[rbase + r] = sqp;
  }
}

// K2: 16-row i-blocks (was 32). Halves per-block state: one lst, one merge
// pass, LDS 35.3KB -> 17.6KB => 8 blocks/CU; grid 1024 -> 2048 => 32 waves/CU
// resident (was 16). Same total insertion work, ~2x latency hiding.
__global__ __launch_bounds__(256, 4) void k_knn(const unsigned short* __restrict__ sfb,
                                                const float* __restrict__ sq,
                                                float* __restrict__ tops) {
  const int tid = threadIdx.x;
  const int wave = tid >> 6, lane = tid & 63;
  const int q = lane >> 4, n = lane & 15;
  const int ib = (blockIdx.x >> 2) * 16;
  const int js = blockIdx.x & 3;
  const short8* sfv = (const short8*)sfb;

  short8 b0 = sfv[(ib + n) * 8 + q];
  short8 b1 = sfv[(ib + n) * 8 + 4 + q];

  float lst0[16];
#pragma unroll
  for (int k = 0; k < 16; ++k) lst0[k] = 3.0e38f;

  const int j0 = js * 2048 + wave * 512;
  short8 A0 = sfv[(j0 + n) * 8 + q];
  short8 A1 = sfv[(j0 + n) * 8 + 4 + q];
  floatx4 s4 = *(const floatx4*)(sq + j0 + q * 4);

#pragma unroll 2
  for (int jt = 0; jt < 512; jt += 16) {
    const int jn = j0 + jt + 16;   // final prefetch overruns into ws scratch: harmless
    short8 nA0 = sfv[(jn + n) * 8 + q];
    short8 nA1 = sfv[(jn + n) * 8 + 4 + q];
    floatx4 ns4 = *(const floatx4*)(sq + jn + q * 4);
    __builtin_amdgcn_sched_barrier(0);

    floatx4 acc0 = {0, 0, 0, 0};
    acc0 = __builtin_amdgcn_mfma_f32_16x16x32_bf16(A0, b0, acc0, 0, 0, 0);
    acc0 = __builtin_amdgcn_mfma_f32_16x16x32_bf16(A1, b1, acc0, 0, 0, 0);

#pragma unroll
    for (int r = 0; r < 4; ++r) {
      float c = fmaf(-2.0f, acc0[r], s4[r]);   // key = sq_j - 2*dot
#pragma unroll
      for (int k = 15; k >= 1; --k)
        lst0[k] = __builtin_amdgcn_fmed3f(lst0[k], lst0[k - 1], c);
      lst0[0] = fminf(lst0[0], c);
    }
    A0 = nA0; A1 = nA1; s4 = ns4;
  }

  // stride 275 words: 275 % 32 = 19 (odd) -> the 16 head-readers (sub lanes)
  // land on 16 distinct banks; write side is <=4-way (free-ish, 16 stores).
  __shared__ unsigned lists[16 * 275];
  const int sl = wave * 4 + q;
#pragma unroll
  for (int k = 0; k < 16; ++k)
    lists[sl * 275 + n * 17 + k] = packkey(lst0[k], sl);
  __syncthreads();

  const int sub = lane & 15;
  const int rr = wave * 4 + (lane >> 4);       // 0..15
  int p = 0;
  unsigned h = lists[sub * 275 + rr * 17];
  float* trow = tops + ((size_t)(ib + rr) * 4 + js) * 16;
#pragma unroll 1
  for (int it = 0; it < 16; ++it) {
    unsigned u = h;
#pragma unroll
    for (int off = 1; off < 16; off <<= 1) {
      unsigned u2 = __shfl_xor(u, off, 64);
      u = (u2 < u) ? u2 : u;
    }
    if (sub == 0) trow[it] = unpackkey(u);
    if ((u & 15u) == (unsigned)sub) { ++p; h = lists[sub * 275 + rr * 17 + p]; }
  }
}

// K2b: unchanged (tops layout still [8192][4][16]).
__global__ __launch_bounds__(256) void k_merge(const float* __restrict__ tops,
                                               const float* __restrict__ sq,
                                               float* __restrict__ intrew,
                                               float* __restrict__ psum) {
  const int tid = threadIdx.x;
  __shared__ float buf[32][68];
  const int ib = blockIdx.x * 32;
  const floatx4* tv = (const floatx4*)(tops + (size_t)ib * 64);
#pragma unroll
  for (int k = 0; k < 2; ++k) {
    int f4 = k * 256 + tid;                  // 0..511 (32 rows x 16 float4)
    floatx4 v = tv[f4];
    int r = f4 >> 4, c = (f4 & 15) * 4;
    *(floatx4*)(&buf[r][c]) = v;
  }
  __syncthreads();
  __shared__ float rsum[1];
  if (tid < 32) {
    const float* bb = buf[tid];
    const int row = ib + tid;
    const float sqr = sq[row];
    int c0 = 1, c1 = 17, c2 = 33, c3 = 49;
    float h0 = bb[0], h1 = bb[16], h2 = bb[32], h3 = bb[48];
    float sum = 0.0f;
#pragma unroll 1
    for (int it = 0; it < 16; ++it) {
      float m = fminf(fminf(h0, h1), fminf(h2, h3));
      sum += sqrtf(fmaxf(sqr + m, 1e-12f));
      if (m == h0)      { h0 = (c0 < 16) ? bb[c0] : 3.0e38f; ++c0; }
      else if (m == h1) { h1 = (c1 < 32) ? bb[c1] : 3.0e38f; ++c1; }
      else if (m == h2) { h2 = (c2 < 48) ? bb[c2] : 3.0e38f; ++c2; }
      else              { h3 = (c3 < 64) ? bb[c3] : 3.0e38f; ++c3; }
    }
    float ir = sum * (1.0f / 16.0f);
    intrew[row] = ir;
    float w = ir;
#pragma unroll
    for (int off = 1; off < 32; off <<= 1) w += __shfl_xor(w, off, 64);
    if (tid == 0) rsum[0] = w;
  }
  __syncthreads();
  if (tid == 0) psum[blockIdx.x] = rsum[0];
}

// K3: StreamNorm + add reward (psum has 256 block sums; shuffle+LDS reduce)
__global__ __launch_bounds__(256) void k_final(const float* __restrict__ reward,
                                               const float* __restrict__ intrew,
                                               const float* __restrict__ psum,
                                               float* __restrict__ out) {
  const int tid = threadIdx.x;
  const int wave = tid >> 6, lane = tid & 63;
  float v = psum[tid];                       // 256 entries
#pragma unroll
  for (int off = 1; off < 64; off <<= 1) v += __shfl_xor(v, off, 64);
  __shared__ float ws4[4];
  if (lane == 0) ws4[wave] = v;
  __syncthreads();
  float total = ws4[0] + ws4[1] + ws4[2] + ws4[3];
  float mean = total * (1.0f / 8192.0f);
  float mag = 0.99f + 0.01f * mean;
  float inv = 1.0f / (mag + 1e-8f);
  int i = blockIdx.x * 256 + tid;            // 0..8191
  int b = i >> 9, ti = i & 511;
  out[i] = reward[b * TT + ti] + intrew[i] * inv;
}

extern "C" void kernel_launch(void* const* d_in, const int* in_sizes, int n_in,
                              void* d_out, int out_size, void* d_ws, size_t ws_size,
                              hipStream_t stream) {
  const float* feat   = (const float*)d_in[0];
  const float* reward = (const float*)d_in[1];
  const float* proj   = (const float*)d_in[2];
  float* out = (float*)d_out;

  char* ws = (char*)d_ws;
  unsigned short* sfb   = (unsigned short*)ws;                 // 1 MB: sf bf16 [8192][64]
  float* sq             = (float*)(ws + 0x100000);             // 32 KB
  float* intrew         = (float*)(ws + 0x110000);             // 32 KB
  float* psum           = (float*)(ws + 0x120000);             // 1 KB (256 floats)
  unsigned short* prepB = (unsigned short*)(ws + 0x130000);    // 192 KB: proj bf16 B-frags
  float* tops           = (float*)(ws + 0x160000);             // 2 MB: [8192][4][16]

  k_prep<<<48, 256, 0, stream>>>(proj, prepB);
  k_sf<<<512, 256, 0, stream>>>(feat, prepB, sfb, sq);
  k_knn<<<2048, 256, 0, stream>>>(sfb, sq, tops);
  k_merge<<<256, 256, 0, stream>>>(tops, sq, intrew, psum);
  k_final<<<32, 256, 0, stream>>>(reward, intrew, psum, out);
}

// Round 2
// 160.152 us; speedup vs baseline: 1.1211x; 1.1211x over previous
//
#include <hip/hip_runtime.h>
#include <hip/hip_bf16.h>
#include <stdint.h>

typedef __attribute__((ext_vector_type(8))) short short8;
typedef __attribute__((ext_vector_type(4))) float floatx4;

#define FEAT_DIM 1536
#define QD 64
#define NROWS 8192
#define TT 513

__device__ __forceinline__ unsigned short f2bf(float x) {
  union { float f; unsigned u; } t; t.f = x;
  unsigned r = t.u + 0x7fffu + ((t.u >> 16) & 1u);
  return (unsigned short)(r >> 16);
}
__device__ __forceinline__ float bf2f(unsigned short u) {
  union { float f; unsigned u; } t; t.u = ((unsigned)u) << 16;
  return t.f;
}
// monotone float->uint map (order-preserving), low 4 bits freed for an index
__device__ __forceinline__ unsigned packkey(float f, int idx) {
  unsigned x = __float_as_uint(f);
  unsigned m = (unsigned)((int)x >> 31);
  unsigned u = x ^ (m | 0x80000000u);
  return (u & ~15u) | (unsigned)idx;
}
__device__ __forceinline__ float unpackkey(unsigned u) {
  u &= ~15u;
  unsigned x = (u & 0x80000000u) ? (u ^ 0x80000000u) : ~u;
  return __uint_as_float(x);
}

// K0: one-time proj -> bf16 in MFMA B-fragment order.
// prepB[((c*4+sub)*16+n)*4+q][j] = bf16(proj[(c*32+q*8+j)*64 + sub*16 + n])
__global__ __launch_bounds__(256) void k_prep(const float* __restrict__ proj,
                                              unsigned short* __restrict__ prepB) {
  int t = blockIdx.x * 256 + threadIdx.x;   // 0..12287
  int q = t & 3, nn = (t >> 2) & 15, sub = (t >> 6) & 3, c = t >> 8;
  const float* src = proj + (size_t)(c * 32 + q * 8) * QD + sub * 16 + nn;
  union { unsigned short u[8]; short8 v; } P;
#pragma unroll
  for (int j = 0; j < 8; ++j) P.u[j] = f2bf(src[j * QD]);
  *(short8*)(prepB + (size_t)t * 8) = P.v;
}

// K1a: sf partials. K split across blocks (4 quarters of 384) so the grid is
// 2048 (~6 blocks/CU) instead of 512 (2/CU): k_sf was HBM-LATENCY-bound with
// only 8 waves/CU in flight. Each block writes an f32 [16][64] partial into
// its own disjoint buffer (no atomics, no zero-init needed).
__global__ __launch_bounds__(256, 4) void k_sf_part(const float* __restrict__ feat,
                                                    const unsigned short* __restrict__ prepB,
                                                    float* __restrict__ sff32) {
  const int tid = threadIdx.x;
  const int wave = tid >> 6, lane = tid & 63;
  const int q = lane >> 4, n = lane & 15;
  const int rowblk = blockIdx.x >> 2, kp = blockIdx.x & 3;
  const int rbase = rowblk * 16;
  const int row = rbase + n;
  const int b = row >> 9, ti = row & 511;
  const float* fb = feat + (size_t)(b * TT + ti) * FEAT_DIM;
  const int kw = kp * 384 + wave * 96;              // this wave's K base
  const short8* pb = (const short8*)prepB + (size_t)(kw >> 5) * 256 + n * 4 + q;

  floatx4 acc0 = {0,0,0,0}, acc1 = {0,0,0,0}, acc2 = {0,0,0,0}, acc3 = {0,0,0,0};

  int koff = kw + q * 8;
  floatx4 f0 = *(const floatx4*)(fb + koff);
  floatx4 f1 = *(const floatx4*)(fb + koff + 4);
  floatx4 g0 = *(const floatx4*)(fb + FEAT_DIM + koff);
  floatx4 g1 = *(const floatx4*)(fb + FEAT_DIM + koff + 4);

#pragma unroll
  for (int ks = 0; ks < 3; ++ks) {
    floatx4 nf0, nf1, ng0, ng1;
    if (ks < 2) {
      int ko = kw + (ks + 1) * 32 + q * 8;
      nf0 = *(const floatx4*)(fb + ko);
      nf1 = *(const floatx4*)(fb + ko + 4);
      ng0 = *(const floatx4*)(fb + FEAT_DIM + ko);
      ng1 = *(const floatx4*)(fb + FEAT_DIM + ko + 4);
    }
    const short8* pc = pb + ks * 256;
    short8 B0 = pc[0], B1 = pc[64], B2 = pc[128], B3 = pc[192];
    union { unsigned short u[8]; short8 v; } A;
#pragma unroll
    for (int j = 0; j < 4; ++j) A.u[j] = f2bf(0.5f * (f0[j] + g0[j]));
#pragma unroll
    for (int j = 0; j < 4; ++j) A.u[4 + j] = f2bf(0.5f * (f1[j] + g1[j]));
    acc0 = __builtin_amdgcn_mfma_f32_16x16x32_bf16(A.v, B0, acc0, 0, 0, 0);
    acc1 = __builtin_amdgcn_mfma_f32_16x16x32_bf16(A.v, B1, acc1, 0, 0, 0);
    acc2 = __builtin_amdgcn_mfma_f32_16x16x32_bf16(A.v, B2, acc2, 0, 0, 0);
    acc3 = __builtin_amdgcn_mfma_f32_16x16x32_bf16(A.v, B3, acc3, 0, 0, 0);
    if (ks < 2) { f0 = nf0; f1 = nf1; g0 = ng0; g1 = ng1; }
  }

  __shared__ float part[4][16][64];
#pragma unroll
  for (int r = 0; r < 4; ++r) {
    part[wave][q * 4 + r][0 * 16 + n] = acc0[r];
    part[wave][q * 4 + r][1 * 16 + n] = acc1[r];
    part[wave][q * 4 + r][2 * 16 + n] = acc2[r];
    part[wave][q * 4 + r][3 * 16 + n] = acc3[r];
  }
  __syncthreads();
  {
    const int r = tid >> 4;
    const int c0 = (tid & 15) * 4;
    floatx4 o;
#pragma unroll
    for (int j = 0; j < 4; ++j)
      o[j] = ((part[0][r][c0 + j] + part[1][r][c0 + j]) +
               part[2][r][c0 + j]) + part[3][r][c0 + j];
    *(floatx4*)(sff32 + ((size_t)kp * NROWS + rbase + r) * QD + c0) = o;
  }
}

// K1b: sum the 4 K-partials (ascending K order, matching the old association),
// round to bf16 (identical f2bf), emit sfb + sq (identical 16-lane reduce).
__global__ __launch_bounds__(256) void k_sf_fin(const float* __restrict__ sff32,
                                                unsigned short* __restrict__ sfb,
                                                float* __restrict__ sq) {
  const int tid = threadIdx.x;
  const int rbase = blockIdx.x * 16;
  const int r = tid >> 4, c0 = (tid & 15) * 4;
  const size_t e = ((size_t)rbase + r) * QD + c0;
  floatx4 v0 = *(const floatx4*)(sff32 + e);
  floatx4 v1 = *(const floatx4*)(sff32 + (size_t)NROWS * QD + e);
  floatx4 v2 = *(const floatx4*)(sff32 + 2 * (size_t)NROWS * QD + e);
  floatx4 v3 = *(const floatx4*)(sff32 + 3 * (size_t)NROWS * QD + e);
  float sqp = 0.0f;
  union { unsigned short u[4]; uint2 d; } P;
#pragma unroll
  for (int j = 0; j < 4; ++j) {
    float v = ((v0[j] + v1[j]) + v2[j]) + v3[j];
    P.u[j] = f2bf(v);
    float bv = bf2f(P.u[j]);
    sqp += bv * bv;
  }
  *(uint2*)(sfb + e) = P.d;
#pragma unroll
  for (int off = 1; off < 16; off <<= 1) sqp += __shfl_xor(sqp, off, 64);
  if ((tid & 15) == 0) sq[rbase + r] = sqp;
}

// K2: EXACT round-0 k_knn (measured 60us; the 16-row variant A/B-regressed to
// 80us: halved per-wave ILP of the insertion chains was the loss, not waves).
__global__ __launch_bounds__(256, 4) void k_knn(const unsigned short* __restrict__ sfb,
                                                const float* __restrict__ sq,
                                                float* __restrict__ tops) {
  const int tid = threadIdx.x;
  const int wave = tid >> 6, lane = tid & 63;
  const int q = lane >> 4, n = lane & 15;
  const int ib = (blockIdx.x >> 2) * 32;
  const int js = blockIdx.x & 3;
  const short8* sfv = (const short8*)sfb;

  short8 b0 = sfv[(ib + n) * 8 + q];
  short8 b1 = sfv[(ib + n) * 8 + 4 + q];
  short8 b2 = sfv[(ib + 16 + n) * 8 + q];
  short8 b3 = sfv[(ib + 16 + n) * 8 + 4 + q];

  float lst0[16], lst1[16];
#pragma unroll
  for (int k = 0; k < 16; ++k) { lst0[k] = 3.0e38f; lst1[k] = 3.0e38f; }

  const int j0 = js * 2048 + wave * 512;
  short8 A0 = sfv[(j0 + n) * 8 + q];
  short8 A1 = sfv[(j0 + n) * 8 + 4 + q];
  floatx4 s4 = *(const floatx4*)(sq + j0 + q * 4);

  for (int jt = 0; jt < 512; jt += 16) {
    const int jn = j0 + jt + 16;   // final prefetch overruns into ws scratch: harmless
    short8 nA0 = sfv[(jn + n) * 8 + q];
    short8 nA1 = sfv[(jn + n) * 8 + 4 + q];
    floatx4 ns4 = *(const floatx4*)(sq + jn + q * 4);
    __builtin_amdgcn_sched_barrier(0);

    floatx4 acc0 = {0, 0, 0, 0};
    acc0 = __builtin_amdgcn_mfma_f32_16x16x32_bf16(A0, b0, acc0, 0, 0, 0);
    acc0 = __builtin_amdgcn_mfma_f32_16x16x32_bf16(A1, b1, acc0, 0, 0, 0);
    floatx4 acc1 = {0, 0, 0, 0};
    acc1 = __builtin_amdgcn_mfma_f32_16x16x32_bf16(A0, b2, acc1, 0, 0, 0);
    acc1 = __builtin_amdgcn_mfma_f32_16x16x32_bf16(A1, b3, acc1, 0, 0, 0);

#pragma unroll
    for (int r = 0; r < 4; ++r) {
      float c = fmaf(-2.0f, acc0[r], s4[r]);   // key = sq_j - 2*dot
#pragma unroll
      for (int k = 15; k >= 1; --k)
        lst0[k] = __builtin_amdgcn_fmed3f(lst0[k], lst0[k - 1], c);
      lst0[0] = fminf(lst0[0], c);
    }
#pragma unroll
    for (int r = 0; r < 4; ++r) {
      float c = fmaf(-2.0f, acc1[r], s4[r]);
#pragma unroll
      for (int k = 15; k >= 1; --k)
        lst1[k] = __builtin_amdgcn_fmed3f(lst1[k], lst1[k - 1], c);
      lst1[0] = fminf(lst1[0], c);
    }
    A0 = nA0; A1 = nA1; s4 = ns4;
  }

  __shared__ unsigned lists[16 * 547];
  const int sl = wave * 4 + q;
#pragma unroll
  for (int k = 0; k < 16; ++k) {
    lists[sl * 547 + n * 17 + k] = packkey(lst0[k], sl);
    lists[sl * 547 + (n + 16) * 17 + k] = packkey(lst1[k], sl);
  }
  __syncthreads();

  const int sub = lane & 15;
#pragma unroll 1
  for (int pass = 0; pass < 2; ++pass) {
    const int rr = pass * 16 + wave * 4 + (lane >> 4);   // 0..31
    int p = 0;
    unsigned h = lists[sub * 547 + rr * 17];
    float* trow = tops + ((size_t)(ib + rr) * 4 + js) * 16;
#pragma unroll 1
    for (int it = 0; it < 16; ++it) {
      unsigned u = h;
#pragma unroll
      for (int off = 1; off < 16; off <<= 1) {
        unsigned u2 = __shfl_xor(u, off, 64);
        u = (u2 < u) ? u2 : u;
      }
      if (sub == 0) trow[it] = unpackkey(u);
      if ((u & 15u) == (unsigned)sub) { ++p; h = lists[sub * 547 + rr * 17 + p]; }
    }
  }
}

// K2b: unchanged round-0 merge (tops layout [8192][4][16]).
__global__ __launch_bounds__(256) void k_merge(const float* __restrict__ tops,
                                               const float* __restrict__ sq,
                                               float* __restrict__ intrew,
                                               float* __restrict__ psum) {
  const int tid = threadIdx.x;
  __shared__ float buf[32][68];
  const int ib = blockIdx.x * 32;
  const floatx4* tv = (const floatx4*)(tops + (size_t)ib * 64);
#pragma unroll
  for (int k = 0; k < 2; ++k) {
    int f4 = k * 256 + tid;                  // 0..511 (32 rows x 16 float4)
    floatx4 v = tv[f4];
    int r = f4 >> 4, c = (f4 & 15) * 4;
    *(floatx4*)(&buf[r][c]) = v;
  }
  __syncthreads();
  __shared__ float rsum[1];
  if (tid < 32) {
    const float* bb = buf[tid];
    const int row = ib + tid;
    const float sqr = sq[row];
    int c0 = 1, c1 = 17, c2 = 33, c3 = 49;
    float h0 = bb[0], h1 = bb[16], h2 = bb[32], h3 = bb[48];
    float sum = 0.0f;
#pragma unroll 1
    for (int it = 0; it < 16; ++it) {
      float m = fminf(fminf(h0, h1), fminf(h2, h3));
      sum += sqrtf(fmaxf(sqr + m, 1e-12f));
      if (m == h0)      { h0 = (c0 < 16) ? bb[c0] : 3.0e38f; ++c0; }
      else if (m == h1) { h1 = (c1 < 32) ? bb[c1] : 3.0e38f; ++c1; }
      else if (m == h2) { h2 = (c2 < 48) ? bb[c2] : 3.0e38f; ++c2; }
      else              { h3 = (c3 < 64) ? bb[c3] : 3.0e38f; ++c3; }
    }
    float ir = sum * (1.0f / 16.0f);
    intrew[row] = ir;
    float w = ir;
#pragma unroll
    for (int off = 1; off < 32; off <<= 1) w += __shfl_xor(w, off, 64);
    if (tid == 0) rsum[0] = w;
  }
  __syncthreads();
  if (tid == 0) psum[blockIdx.x] = rsum[0];
}

// K3: StreamNorm + add reward (psum has 256 block sums; shuffle+LDS reduce)
__global__ __launch_bounds__(256) void k_final(const float* __restrict__ reward,
                                               const float* __restrict__ intrew,
                                               const float* __restrict__ psum,
                                               float* __restrict__ out) {
  const int tid = threadIdx.x;
  const int wave = tid >> 6, lane = tid & 63;
  float v = psum[tid];                       // 256 entries
#pragma unroll
  for (int off = 1; off < 64; off <<= 1) v += __shfl_xor(v, off, 64);
  __shared__ float ws4[4];
  if (lane == 0) ws4[wave] = v;
  __syncthreads();
  float total = ws4[0] + ws4[1] + ws4[2] + ws4[3];
  float mean = total * (1.0f / 8192.0f);
  float mag = 0.99f + 0.01f * mean;
  float inv = 1.0f / (mag + 1e-8f);
  int i = blockIdx.x * 256 + tid;            // 0..8191
  int b = i >> 9, ti = i & 511;
  out[i] = reward[b * TT + ti] + intrew[i] * inv;
}

extern "C" void kernel_launch(void* const* d_in, const int* in_sizes, int n_in,
                              void* d_out, int out_size, void* d_ws, size_t ws_size,
                              hipStream_t stream) {
  const float* feat   = (const float*)d_in[0];
  const float* reward = (const float*)d_in[1];
  const float* proj   = (const float*)d_in[2];
  float* out = (float*)d_out;

  char* ws = (char*)d_ws;
  unsigned short* sfb   = (unsigned short*)ws;                 // 1 MB: sf bf16 [8192][64]
  float* sq             = (float*)(ws + 0x100000);             // 32 KB
  float* intrew         = (float*)(ws + 0x110000);             // 32 KB
  float* psum           = (float*)(ws + 0x120000);             // 1 KB (256 floats)
  unsigned short* prepB = (unsigned short*)(ws + 0x130000);    // 192 KB: proj bf16 B-frags
  float* tops           = (float*)(ws + 0x160000);             // 2 MB: [8192][4][16]
  float* sff32          = (float*)(ws + 0x360000);             // 8 MB: [4][8192][64] f32 partials

  k_prep<<<48, 256, 0, stream>>>(proj, prepB);
  k_sf_part<<<2048, 256, 0, stream>>>(feat, prepB, sff32);
  k_sf_fin<<<512, 256, 0, stream>>>(sff32, sfb, sq);
  k_knn<<<1024, 256, 0, stream>>>(sfb, sq, tops);
  k_merge<<<256, 256, 0, stream>>>(tops, sq, intrew, psum);
  k_final<<<32, 256, 0, stream>>>(reward, intrew, psum, out);
}